// Round 3
// baseline (464.786 us; speedup 1.0000x reference)
//
#include <hip/hip_runtime.h>
#include <math.h>

#define NB 4
#define DD 128
#define HH 128
#define WW 128
#define VOX (DD*HH*WW)          // 2097152 = 2^21
#define NVOX (NB*VOX)           // 8388608
#define ROLL 8                  // outputs per thread along conv axis (z-smooth)
#define NTHR (NVOX/ROLL)        // 1048576

struct GaussW { float w[7]; };

// ---------------------------------------------------------------------------
// Register-rolling 7-tap 1D conv along z (SHIFT=14). Each thread computes
// ROLL consecutive outputs, loading ROLL+6 inputs once.
template <int SHIFT>
__global__ void smooth_roll_kernel(const float* __restrict__ in, float* __restrict__ out,
                                   GaussW gw) {
    const int stride = 1 << SHIFT;
    int t = blockIdx.x * blockDim.x + threadIdx.x;
    if (t >= NTHR) return;
    int low  = t & (stride - 1);
    int rest = t >> SHIFT;
    int cblk = rest & 15;
    int hi   = rest >> 4;
    int c0   = cblk * ROLL;
    size_t base = ((size_t)hi << (SHIFT + 7)) | (size_t)low;

    float r[ROLL + 6];
#pragma unroll
    for (int j = 0; j < ROLL + 6; ++j) {
        int cc = c0 - 3 + j;
        r[j] = (cc >= 0 && cc < 128) ? in[base + ((size_t)cc << SHIFT)] : 0.f;
    }
#pragma unroll
    for (int i = 0; i < ROLL; ++i) {
        float acc = 0.f;
#pragma unroll
        for (int k = 0; k < 7; ++k) acc += gw.w[k] * r[i + k];
        out[base + ((size_t)(c0 + i) << SHIFT)] = acc;
    }
}

// ---------------------------------------------------------------------------
// Fused y-conv + x-conv over one (n, z, y-chunk) slab.
// Block = 256 threads. Stages 38 input rows (y0-3 .. y0+34) of 128 floats in
// LDS, y-convolves into a 32x128 mid buffer, then x-convolves mid -> global.
#define YC 32
__global__ void yx_smooth_kernel(const float* __restrict__ in, float* __restrict__ out,
                                 GaussW gw) {
    __shared__ float in_t[YC + 6][WW];   // 38*128*4 = 19456 B
    __shared__ float mid[YC][WW];        // 32*128*4 = 16384 B

    int b = blockIdx.x;                  // NB*DD*(HH/YC) = 2048
    int yc = b & 3;
    int z  = (b >> 2) & 127;
    int n  = b >> 9;
    int y0 = yc * YC;
    size_t slice = (((size_t)n << 7) | z) << 14;   // base of (n,z) slice
    int tid = threadIdx.x;

    // stage input rows (zero beyond y bounds)
    for (int i = tid; i < (YC + 6) * WW; i += 256) {
        int r  = i >> 7;
        int gx = i & 127;
        int gy = y0 - 3 + r;
        in_t[r][gx] = (gy >= 0 && gy < HH) ? in[slice + ((size_t)gy << 7) + gx] : 0.f;
    }
    __syncthreads();

    // y-conv -> mid
    for (int i = tid; i < YC * WW; i += 256) {
        int yo = i >> 7;
        int x  = i & 127;
        float acc = 0.f;
#pragma unroll
        for (int k = 0; k < 7; ++k) acc += gw.w[k] * in_t[yo + k][x];
        mid[yo][x] = acc;
    }
    __syncthreads();

    // x-conv -> global
    for (int i = tid; i < YC * WW; i += 256) {
        int yo = i >> 7;
        int x  = i & 127;
        float acc = 0.f;
#pragma unroll
        for (int k = 0; k < 7; ++k) {
            int xx = x - 3 + k;
            if (xx >= 0 && xx < WW) acc += gw.w[k] * mid[yo][xx];
        }
        out[slice + ((size_t)(y0 + yo) << 7) + x] = acc;
    }
}

// ---------------------------------------------------------------------------
// forward diff with duplicated last element (matches jnp.diff + concat(last))
__device__ __forceinline__ float fd(const float* __restrict__ f, int base, int c, int stride) {
    int ip = (c < 127) ? base + stride : base;
    int im = (c < 127) ? base          : base - stride;
    return f[ip] - f[im];
}

// Fused |curl(v)| + z-smooth. Thread owns a 16-z output window of one
// (n,y,x) column: computes 22 curl values (z0-3 .. z0+18) in registers,
// then emits 16 z-smoothed values. v layout (N,3,D,H,W).
#define ZC 16
__global__ void curl_zsmooth_kernel(const float* __restrict__ v, float* __restrict__ out,
                                    GaussW gw) {
    int idx = blockIdx.x * blockDim.x + threadIdx.x;  // NB*(DD/ZC)*HH*WW = 524288
    int x  = idx & 127;
    int y  = (idx >> 7) & 127;
    int zc = (idx >> 14) & 7;
    int n  = idx >> 17;
    int z0 = zc * ZC;
    const float* u  = v + (size_t)n * 3 * VOX;
    const float* vv = u + VOX;
    const float* w  = vv + VOX;
    int byx = (y << 7) | x;

    float r[ZC + 6];
#pragma unroll
    for (int jj = 0; jj < ZC + 6; ++jj) {
        int j = z0 - 3 + jj;
        float c = 0.f;
        if (j >= 0 && j < 128) {       // wave-uniform (zc uniform across wave)
            int base = (j << 14) | byx;
            // axes of (N,D,H,W): D(z) stride 16384, H(y) stride 128, W(x) stride 1
            float cu = fd(w,  base, y, 128)   - fd(vv, base, j, 16384); // dw/dy - dv/dz
            float cv = fd(u,  base, j, 16384) - fd(w,  base, x, 1);     // du/dz - dw/dx
            float cw = fd(vv, base, x, 1)     - fd(u,  base, y, 128);   // dv/dx - du/dy
            c = sqrtf(cu * cu + cv * cv + cw * cw);
        }
        r[jj] = c;
    }
#pragma unroll
    for (int i = 0; i < ZC; ++i) {
        float acc = 0.f;
#pragma unroll
        for (int k = 0; k < 7; ++k) acc += gw.w[k] * r[i + k];
        out[((size_t)n << 21) | ((size_t)(z0 + i) << 14) | byx] = acc;
    }
}

// ---------------------------------------------------------------------------
// Per (n,y,x) column: flip along z, cumsum -> transmittance, trapezoid, clip.
__global__ void render_kernel(const float* __restrict__ ds, const float* __restrict__ vn,
                              float* __restrict__ out) {
    int idx = blockIdx.x * blockDim.x + threadIdx.x;  // NB*HH*WW = 65536
    if (idx >= NB * HH * WW) return;
    int x = idx & 127;
    int y = (idx >> 7) & 127;
    int n = idx >> 14;
    size_t volbase = (size_t)n * VOX + ((size_t)y << 7) + x;

    float xacc = 0.f, acc = 0.f, tp = 0.f, vp = 0.f;
    for (int k = 0; k < 128; ++k) {
        int z = 127 - k;
        size_t off = volbase + ((size_t)z << 14);
        xacc += ds[off];
        float xc = 20.f * xacc;
        float tk = (xc + 1.f) * expf(-xc);
        float vk = vn[off];
        if (k == 0) {
            acc = (1.f - tk) * vk;
        } else {
            acc += (tp - tk) * (vp + vk) * 0.5f;
        }
        tp = tk; vp = vk;
    }
    out[idx] = fminf(fmaxf(acc, 0.f), 1.f);
}

// ---------------------------------------------------------------------------
extern "C" void kernel_launch(void* const* d_in, const int* in_sizes, int n_in,
                              void* d_out, int out_size, void* d_ws, size_t ws_size,
                              hipStream_t stream) {
    const float* d = (const float*)d_in[0];   // (4,1,128,128,128)
    const float* v = (const float*)d_in[1];   // (4,3,128,128,128)
    float* out = (float*)d_out;               // (4,1,128,128)

    GaussW gw;
    {
        double g[7], s = 0.0;
        for (int i = 0; i < 7; ++i) {
            double t = (i - 3) / 1.6;
            g[i] = exp(-t * t / 2.0);
            s += g[i];
        }
        for (int i = 0; i < 7; ++i) gw.w[i] = (float)(g[i] / s);
    }

    float* ws0 = (float*)d_ws;        // ds final
    float* ws1 = ws0 + NVOX;          // scratch
    float* ws2 = ws1 + NVOX;          // vn final

    const int TB = 256;

    // ds = smooth(d): z pass (register-rolled), then fused y+x slab pass
    smooth_roll_kernel<14><<<NTHR / TB, TB, 0, stream>>>(d, ws1, gw);
    yx_smooth_kernel<<<NB * DD * (HH / YC), TB, 0, stream>>>(ws1, ws0, gw);

    // vn = smooth(|curl(v)|): fused curl+z-smooth, then fused y+x slab pass
    curl_zsmooth_kernel<<<(NB * (DD / ZC) * HH * WW) / TB, TB, 0, stream>>>(v, ws1, gw);
    yx_smooth_kernel<<<NB * DD * (HH / YC), TB, 0, stream>>>(ws1, ws2, gw);

    // final render reduction
    render_kernel<<<(NB * HH * WW) / TB, TB, 0, stream>>>(ws0, ws2, out);
}

// Round 4
// 258.463 us; speedup vs baseline: 1.7983x; 1.7983x over previous
//
#include <hip/hip_runtime.h>
#include <math.h>

#define NB 4
#define DD 128
#define HH 128
#define WW 128
#define VOX (DD*HH*WW)          // 2097152 = 2^21
#define NVOX (NB*VOX)           // 8388608
#define ROLL 8                  // outputs per thread along conv axis
#define NTHR (NVOX/ROLL)        // 1048576

struct GaussW { float w[7]; };

// ---------------------------------------------------------------------------
// Register-rolling 7-tap 1D conv: each thread computes ROLL consecutive
// outputs along the axis, loading ROLL+6 inputs once (1.75 loads/output).
// SHIFT: bit position of the axis in the linear index (x=0, y=7, z=14).
template <int SHIFT>
__global__ void smooth_roll_kernel(const float* __restrict__ in, float* __restrict__ out,
                                   GaussW gw) {
    const int stride = 1 << SHIFT;
    int t = blockIdx.x * blockDim.x + threadIdx.x;
    if (t >= NTHR) return;
    int low  = t & (stride - 1);
    int rest = t >> SHIFT;
    int cblk = rest & 15;
    int hi   = rest >> 4;
    int c0   = cblk * ROLL;
    size_t base = ((size_t)hi << (SHIFT + 7)) | (size_t)low;

    float r[ROLL + 6];
#pragma unroll
    for (int j = 0; j < ROLL + 6; ++j) {
        int cc = c0 - 3 + j;
        r[j] = (cc >= 0 && cc < 128) ? in[base + ((size_t)cc << SHIFT)] : 0.f;
    }
#pragma unroll
    for (int i = 0; i < ROLL; ++i) {
        float acc = 0.f;
#pragma unroll
        for (int k = 0; k < 7; ++k) acc += gw.w[k] * r[i + k];
        out[base + ((size_t)(c0 + i) << SHIFT)] = acc;
    }
}

// ---------------------------------------------------------------------------
// |curl(v)| vectorized x4 along x. v layout (N,3,D,H,W).
// Per 4 outputs: 7 float4 loads + 2 scalar loads (vs 40 scalar).
__global__ void curl4_kernel(const float* __restrict__ v, float* __restrict__ vn) {
    int idx = blockIdx.x * blockDim.x + threadIdx.x;  // NVOX/4 = 2097152
    int xq = idx & 31;            // x-quad: x0 = 4*xq
    int y  = (idx >> 5) & 127;
    int z  = (idx >> 12) & 127;
    int n  = idx >> 19;
    int x0 = xq << 2;
    const float* u  = v + (size_t)n * 3 * VOX;
    const float* vv = u + VOX;
    const float* w  = vv + VOX;
    size_t s = ((size_t)z << 14) | ((size_t)y << 7) | (size_t)x0;

    int dy = (y < 127) ? 128 : -128;
    int dz = (z < 127) ? 16384 : -16384;
    float sy = (y < 127) ? 1.f : -1.f;
    float sz = (z < 127) ? 1.f : -1.f;
    int dxp = (xq < 31) ? 4 : 0;   // guard OOB read at the right edge

    const float4 wc  = *(const float4*)(w  + s);
    const float4 wyn = *(const float4*)(w  + s + dy);
    const float4 vc  = *(const float4*)(vv + s);
    const float4 vzn = *(const float4*)(vv + s + dz);
    const float4 uc  = *(const float4*)(u  + s);
    const float4 uzn = *(const float4*)(u  + s + dz);
    const float4 uyn = *(const float4*)(u  + s + dy);
    const float  wxp = w [s + 3 + dxp];   // w[x0+4] (or dummy at edge)
    const float  vxp = vv[s + 3 + dxp];   // vv[x0+4]

    float wca[4] = {wc.x, wc.y, wc.z, wc.w};
    float vca[4] = {vc.x, vc.y, vc.z, vc.w};
    float wya[4] = {wyn.x, wyn.y, wyn.z, wyn.w};
    float vza[4] = {vzn.x, vzn.y, vzn.z, vzn.w};
    float uca[4] = {uc.x, uc.y, uc.z, uc.w};
    float uza[4] = {uzn.x, uzn.y, uzn.z, uzn.w};
    float uya[4] = {uyn.x, uyn.y, uyn.z, uyn.w};
    float wsh[4] = {wc.y, wc.z, wc.w, wxp};
    float vsh[4] = {vc.y, vc.z, vc.w, vxp};

    float4 o;
    float* oa = &o.x;
#pragma unroll
    for (int j = 0; j < 4; ++j) {
        int x = x0 + j;
        float fdxw = (x < 127) ? (wsh[j] - wca[j]) : (wca[3] - wca[2]);
        float fdxv = (x < 127) ? (vsh[j] - vca[j]) : (vca[3] - vca[2]);
        float fdyw = sy * (wya[j] - wca[j]);
        float fdyu = sy * (uya[j] - uca[j]);
        float fdzv = sz * (vza[j] - vca[j]);
        float fdzu = sz * (uza[j] - uca[j]);
        float cu = fdyw - fdzv;   // dw/dy - dv/dz
        float cv = fdzu - fdxw;   // du/dz - dw/dx
        float cw = fdxv - fdyu;   // dv/dx - du/dy
        oa[j] = sqrtf(cu * cu + cv * cv + cw * cw);
    }
    *(float4*)(vn + ((size_t)n * VOX) + s) = o;
}

// ---------------------------------------------------------------------------
// Render: per (n,y,x) column, flip along z, cumsum -> transmittance,
// trapezoid, clip. Batched: 16 z-steps per round => 32 loads in flight.
#define RB 16
__global__ void render_kernel(const float* __restrict__ ds, const float* __restrict__ vn,
                              float* __restrict__ out) {
    int idx = blockIdx.x * blockDim.x + threadIdx.x;  // NB*HH*WW = 65536
    if (idx >= NB * HH * WW) return;
    int x = idx & 127;
    int y = (idx >> 7) & 127;
    int n = idx >> 14;
    size_t volbase = (size_t)n * VOX + ((size_t)y << 7) + x;

    float xacc = 0.f, acc = 0.f, tp = 0.f, vp = 0.f;
    for (int b = 0; b < 128 / RB; ++b) {
        float rds[RB], rvn[RB];
#pragma unroll
        for (int i = 0; i < RB; ++i) {
            int z = 127 - (b * RB + i);           // the flip along D
            size_t off = volbase + ((size_t)z << 14);
            rds[i] = ds[off];
            rvn[i] = vn[off];
        }
#pragma unroll
        for (int i = 0; i < RB; ++i) {
            int k = b * RB + i;
            xacc += rds[i];
            float xc = 20.f * xacc;
            float tk = (xc + 1.f) * __expf(-xc);
            float vk = rvn[i];
            if (k == 0) acc = (1.f - tk) * vk;
            else        acc += (tp - tk) * (vp + vk) * 0.5f;
            tp = tk; vp = vk;
        }
    }
    out[idx] = fminf(fmaxf(acc, 0.f), 1.f);
}

// ---------------------------------------------------------------------------
extern "C" void kernel_launch(void* const* d_in, const int* in_sizes, int n_in,
                              void* d_out, int out_size, void* d_ws, size_t ws_size,
                              hipStream_t stream) {
    const float* d = (const float*)d_in[0];   // (4,1,128,128,128)
    const float* v = (const float*)d_in[1];   // (4,3,128,128,128)
    float* out = (float*)d_out;               // (4,1,128,128)

    GaussW gw;
    {
        double g[7], s = 0.0;
        for (int i = 0; i < 7; ++i) {
            double t = (i - 3) / 1.6;
            g[i] = exp(-t * t / 2.0);
            s += g[i];
        }
        for (int i = 0; i < 7; ++i) gw.w[i] = (float)(g[i] / s);
    }

    float* ws0 = (float*)d_ws;        // ds final
    float* ws1 = ws0 + NVOX;
    float* ws2 = ws1 + NVOX;

    const int TB = 256;

    // ds = smooth(d): z, y, x rolled passes
    smooth_roll_kernel<14><<<NTHR / TB, TB, 0, stream>>>(d,   ws1, gw);
    smooth_roll_kernel<7> <<<NTHR / TB, TB, 0, stream>>>(ws1, ws2, gw);
    smooth_roll_kernel<0> <<<NTHR / TB, TB, 0, stream>>>(ws2, ws0, gw);

    // vn = smooth(|curl(v)|)
    curl4_kernel<<<(NVOX / 4) / TB, TB, 0, stream>>>(v, ws1);
    smooth_roll_kernel<14><<<NTHR / TB, TB, 0, stream>>>(ws1, ws2, gw);
    smooth_roll_kernel<7> <<<NTHR / TB, TB, 0, stream>>>(ws2, ws1, gw);
    smooth_roll_kernel<0> <<<NTHR / TB, TB, 0, stream>>>(ws1, ws2, gw);

    // final render reduction
    render_kernel<<<(NB * HH * WW) / TB, TB, 0, stream>>>(ws0, ws2, out);
}

// Round 5
// 251.261 us; speedup vs baseline: 1.8498x; 1.0287x over previous
//
#include <hip/hip_runtime.h>
#include <math.h>

#define NB 4
#define DD 128
#define HH 128
#define WW 128
#define VOX (DD*HH*WW)          // 2097152 = 2^21
#define NVOX (NB*VOX)           // 8388608
#define ROLL 8

struct GaussW { float w[7]; };

__device__ __forceinline__ float4 f4zero() { float4 z; z.x = z.y = z.z = z.w = 0.f; return z; }

// ---------------------------------------------------------------------------
// 7-tap 1D conv along z (SHIFT=14) or y (SHIFT=7), vectorized float4 along x,
// register-rolled 8 along the conv axis. Thread: 14 float4 loads, 8 float4
// stores. Threads = NVOX/32 = 262144.
template <int SHIFT>
__global__ void smooth_roll4_kernel(const float* __restrict__ in, float* __restrict__ out,
                                    GaussW gw) {
    int t = blockIdx.x * blockDim.x + threadIdx.x;
    int xq   = t & 31;            // x0 = 4*xq
    int cblk = (t >> 5) & 15;     // conv-axis 8-block
    int rest = t >> 9;            // 7 bits other coord + 2 bits n
    int oc   = rest & 127;        // other axis coordinate (y for z-pass, z for y-pass)
    int n    = rest >> 7;
    int c0   = cblk * ROLL;
    const int OSHIFT = (SHIFT == 14) ? 7 : 14;
    size_t base = ((size_t)n << 21) | ((size_t)oc << OSHIFT) | ((size_t)(xq << 2));

    float4 r[ROLL + 6];
#pragma unroll
    for (int j = 0; j < ROLL + 6; ++j) {
        int cc = c0 - 3 + j;
        r[j] = (cc >= 0 && cc < 128)
             ? *(const float4*)(in + base + ((size_t)cc << SHIFT))
             : f4zero();
    }
#pragma unroll
    for (int i = 0; i < ROLL; ++i) {
        float4 a = f4zero();
#pragma unroll
        for (int k = 0; k < 7; ++k) {
            float wk = gw.w[k];
            a.x += wk * r[i + k].x;
            a.y += wk * r[i + k].y;
            a.z += wk * r[i + k].z;
            a.w += wk * r[i + k].w;
        }
        *(float4*)(out + base + ((size_t)(c0 + i) << SHIFT)) = a;
    }
}

// ---------------------------------------------------------------------------
// 7-tap 1D conv along x: thread computes 8 consecutive x via 4 aligned float4
// loads covering [x0-4, x0+12) and 2 float4 stores. Threads = NVOX/8.
__global__ void smooth_rollx_kernel(const float* __restrict__ in, float* __restrict__ out,
                                    GaussW gw) {
    int t = blockIdx.x * blockDim.x + threadIdx.x;
    int cblk = t & 15;
    int x0   = cblk * ROLL;
    size_t row = (size_t)(t >> 4) << 7;   // (n,z,y) row base

    float4 q0 = (cblk > 0)  ? *(const float4*)(in + row + x0 - 4) : f4zero();
    float4 q1 = *(const float4*)(in + row + x0);
    float4 q2 = *(const float4*)(in + row + x0 + 4);
    float4 q3 = (cblk < 15) ? *(const float4*)(in + row + x0 + 8) : f4zero();

    float r[14] = {q0.y, q0.z, q0.w,
                   q1.x, q1.y, q1.z, q1.w,
                   q2.x, q2.y, q2.z, q2.w,
                   q3.x, q3.y, q3.z};
    float o[8];
#pragma unroll
    for (int i = 0; i < 8; ++i) {
        float acc = 0.f;
#pragma unroll
        for (int k = 0; k < 7; ++k) acc += gw.w[k] * r[i + k];
        o[i] = acc;
    }
    *(float4*)(out + row + x0)     = make_float4(o[0], o[1], o[2], o[3]);
    *(float4*)(out + row + x0 + 4) = make_float4(o[4], o[5], o[6], o[7]);
}

// ---------------------------------------------------------------------------
// |curl(v)| vectorized x4 along x. v layout (N,3,D,H,W).
__global__ void curl4_kernel(const float* __restrict__ v, float* __restrict__ vn) {
    int idx = blockIdx.x * blockDim.x + threadIdx.x;  // NVOX/4
    int xq = idx & 31;
    int y  = (idx >> 5) & 127;
    int z  = (idx >> 12) & 127;
    int n  = idx >> 19;
    int x0 = xq << 2;
    const float* u  = v + (size_t)n * 3 * VOX;
    const float* vv = u + VOX;
    const float* w  = vv + VOX;
    size_t s = ((size_t)z << 14) | ((size_t)y << 7) | (size_t)x0;

    int dy = (y < 127) ? 128 : -128;
    int dz = (z < 127) ? 16384 : -16384;
    float sy = (y < 127) ? 1.f : -1.f;
    float sz = (z < 127) ? 1.f : -1.f;
    int dxp = (xq < 31) ? 4 : 0;

    const float4 wc  = *(const float4*)(w  + s);
    const float4 wyn = *(const float4*)(w  + s + dy);
    const float4 vc  = *(const float4*)(vv + s);
    const float4 vzn = *(const float4*)(vv + s + dz);
    const float4 uc  = *(const float4*)(u  + s);
    const float4 uzn = *(const float4*)(u  + s + dz);
    const float4 uyn = *(const float4*)(u  + s + dy);
    const float  wxp = w [s + 3 + dxp];
    const float  vxp = vv[s + 3 + dxp];

    float wca[4] = {wc.x, wc.y, wc.z, wc.w};
    float vca[4] = {vc.x, vc.y, vc.z, vc.w};
    float wya[4] = {wyn.x, wyn.y, wyn.z, wyn.w};
    float vza[4] = {vzn.x, vzn.y, vzn.z, vzn.w};
    float uca[4] = {uc.x, uc.y, uc.z, uc.w};
    float uza[4] = {uzn.x, uzn.y, uzn.z, uzn.w};
    float uya[4] = {uyn.x, uyn.y, uyn.z, uyn.w};
    float wsh[4] = {wc.y, wc.z, wc.w, wxp};
    float vsh[4] = {vc.y, vc.z, vc.w, vxp};

    float4 o;
    float* oa = &o.x;
#pragma unroll
    for (int j = 0; j < 4; ++j) {
        int x = x0 + j;
        float fdxw = (x < 127) ? (wsh[j] - wca[j]) : (wca[3] - wca[2]);
        float fdxv = (x < 127) ? (vsh[j] - vca[j]) : (vca[3] - vca[2]);
        float fdyw = sy * (wya[j] - wca[j]);
        float fdyu = sy * (uya[j] - uca[j]);
        float fdzv = sz * (vza[j] - vca[j]);
        float fdzu = sz * (uza[j] - uca[j]);
        float cu = fdyw - fdzv;
        float cv = fdzu - fdxw;
        float cw = fdxv - fdyu;
        oa[j] = sqrtf(cu * cu + cv * cv + cw * cw);
    }
    *(float4*)(vn + ((size_t)n * VOX) + s) = o;
}

// ---------------------------------------------------------------------------
// Render: per (n,y,x) column, flip z, cumsum -> transmittance, trapezoid, clip.
// Batched 16 z-steps per round for MLP. expf (not __expf) for accuracy margin.
#define RBATCH 16
__global__ void render_kernel(const float* __restrict__ ds, const float* __restrict__ vn,
                              float* __restrict__ out) {
    int idx = blockIdx.x * blockDim.x + threadIdx.x;  // NB*HH*WW = 65536
    if (idx >= NB * HH * WW) return;
    int x = idx & 127;
    int y = (idx >> 7) & 127;
    int n = idx >> 14;
    size_t volbase = (size_t)n * VOX + ((size_t)y << 7) + x;

    float xacc = 0.f, acc = 0.f, tp = 0.f, vp = 0.f;
    for (int b = 0; b < 128 / RBATCH; ++b) {
        float rds[RBATCH], rvn[RBATCH];
#pragma unroll
        for (int i = 0; i < RBATCH; ++i) {
            int z = 127 - (b * RBATCH + i);
            size_t off = volbase + ((size_t)z << 14);
            rds[i] = ds[off];
            rvn[i] = vn[off];
        }
#pragma unroll
        for (int i = 0; i < RBATCH; ++i) {
            int k = b * RBATCH + i;
            xacc += rds[i];
            float xc = 20.f * xacc;
            float tk = (xc + 1.f) * expf(-xc);
            float vk = rvn[i];
            if (k == 0) acc = (1.f - tk) * vk;
            else        acc += (tp - tk) * (vp + vk) * 0.5f;
            tp = tk; vp = vk;
        }
    }
    out[idx] = fminf(fmaxf(acc, 0.f), 1.f);
}

// ---------------------------------------------------------------------------
extern "C" void kernel_launch(void* const* d_in, const int* in_sizes, int n_in,
                              void* d_out, int out_size, void* d_ws, size_t ws_size,
                              hipStream_t stream) {
    const float* d = (const float*)d_in[0];   // (4,1,128,128,128)
    const float* v = (const float*)d_in[1];   // (4,3,128,128,128)
    float* out = (float*)d_out;               // (4,1,128,128)

    GaussW gw;
    {
        double g[7], s = 0.0;
        for (int i = 0; i < 7; ++i) {
            double t = (i - 3) / 1.6;
            g[i] = exp(-t * t / 2.0);
            s += g[i];
        }
        for (int i = 0; i < 7; ++i) gw.w[i] = (float)(g[i] / s);
    }

    float* ws0 = (float*)d_ws;        // ds final
    float* ws1 = ws0 + NVOX;
    float* ws2 = ws1 + NVOX;

    const int TB = 256;
    const int G4  = (NVOX / 32) / TB;   // 1024 blocks, vectorized z/y passes
    const int GX  = (NVOX / 8) / TB;    // 4096 blocks, x pass

    // ds = smooth(d): z, y, x
    smooth_roll4_kernel<14><<<G4, TB, 0, stream>>>(d,   ws1, gw);
    smooth_roll4_kernel<7> <<<G4, TB, 0, stream>>>(ws1, ws2, gw);
    smooth_rollx_kernel    <<<GX, TB, 0, stream>>>(ws2, ws0, gw);

    // vn = smooth(|curl(v)|)
    curl4_kernel<<<(NVOX / 4) / TB, TB, 0, stream>>>(v, ws1);
    smooth_roll4_kernel<14><<<G4, TB, 0, stream>>>(ws1, ws2, gw);
    smooth_roll4_kernel<7> <<<G4, TB, 0, stream>>>(ws2, ws1, gw);
    smooth_rollx_kernel    <<<GX, TB, 0, stream>>>(ws1, ws2, gw);

    // final render reduction
    render_kernel<<<(NB * HH * WW) / TB, TB, 0, stream>>>(ws0, ws2, out);
}